// Round 5
// baseline (468.658 us; speedup 1.0000x reference)
//
#include <hip/hip_runtime.h>

// channel_attention: einsum('bocs,bocm->bocs', x, softmax(score)) contracts m which
// only appears in score => multiplies x by softmax row-sum == 1 (within fp32 eps).
// So q/k/atten are dead code and the problem is exactly:
//   out[g,c,s] = LN_c( sum_m Wp[c][m] * x[g][m][s] + bp[c] ) * gp[c] + betap[c]
// g = b*o in [0,128). Per group: GEMM M=C=128, N=3000, K=128, + per-column LN.
//
// V6. Evidence V1-V5: traffic exact, BW plateaus 2.2-2.6 TB/s at ANY occupancy
// (21/37/80%), all pipes <20% busy, while fillBuffer hits 6.3 TB/s at 10% occ.
// => limiter is the DUTY CYCLE of memory issue: block-wide barriers serialize
// {load|compute|store} phases; in-order vmcnt retirement also chains each
// strip's load-wait behind the prior stores. V6 removes lockstep entirely:
// each WAVE is an autonomous pipeline over 16-row s-strips with a PRIVATE 4 KB
// LDS slot -- no __syncthreads after the one-time W stage. 16 independent
// waves/CU keep loads outstanding continuously. Within a wave, next strip's
// loads are issued BEFORE current stores (load-wait = vmcnt(32), stores fly).
// Store pattern = V4's proven full-sector scalar form (WRITE exact).

#define C    128
#define SEQ  3000
#define NG   128
#define SPG  188                       // strips of 16 s per group (187 full + 8-tail)
#define NSTRIP (NG * SPG)              // 24064
#define NWAVE  4096                    // 512 blocks x 8 waves

typedef float f4 __attribute__((ext_vector_type(4)));
typedef short short8 __attribute__((ext_vector_type(8)));

__device__ __forceinline__ unsigned short f2bf(float f) {
    union { float f; unsigned u; } v; v.f = f;
    unsigned r = v.u + 0x7fffu + ((v.u >> 16) & 1u);   // RNE
    return (unsigned short)(r >> 16);
}

// packed f32x2 -> bf16x2, RNE; dst.lo = bf16(lo), dst.hi = bf16(hi)
__device__ __forceinline__ unsigned cvt2(float lo, float hi) {
    unsigned r;
    asm("v_cvt_pk_bf16_f32 %0, %1, %2" : "=v"(r) : "v"(lo), "v"(hi));
    return r;
}

// 16B-chunk XOR swizzle: injective over 16 consecutive rows (frag reads) and over
// the transpose-write lane pattern, both verified <=2-way (V1-proven).
__device__ __forceinline__ int swz(int row, int chunk) {
    return chunk ^ ((row ^ (row >> 2)) & 15);
}

// Writes W in bf16 with the LDS swizzle pre-applied, so the GEMM kernel's
// W-staging is a pure linear copy.
__global__ void cvt_wp(const float* __restrict__ Wp, unsigned short* __restrict__ out) {
    int i = blockIdx.x * 256 + threadIdx.x;
    if (i >= C * C) return;
    int c = i >> 7, r = i & 127, ch = r >> 3, j = r & 7;
    out[c * C + swz(c, ch) * 8 + j] = f2bf(Wp[i]);
}

__global__ __launch_bounds__(512, 4) void gemm_ln_mfma(
    const float* __restrict__ x,             // [NG][C][SEQ] fp32
    const unsigned short* __restrict__ wbf,  // [C][C] bf16, swizzled chunk layout
    const float* __restrict__ bp,
    const float* __restrict__ gp,
    const float* __restrict__ bep,
    float* __restrict__ out)                 // [NG][C][SEQ] fp32
{
    __shared__ __align__(16) unsigned short Wl[C * C];      // 32 KB, shared W
    __shared__ __align__(16) unsigned short Xs[8][16 * C];  // 8 x 4 KB wave-private

    const int t = threadIdx.x;

    // ---- stage W once (linear copy; swizzle pre-applied by cvt_wp), ONE barrier
    {
        const uint4* wsrc = (const uint4*)wbf;
        uint4* wdst = (uint4*)Wl;
        #pragma unroll
        for (int i = 0; i < 4; ++i) wdst[t + 512 * i] = wsrc[t + 512 * i];
    }
    __syncthreads();
    // From here on: no cross-wave dependencies. Each wave free-runs.

    const int w    = t >> 6;
    const int lane = t & 63;
    // compute roles
    const int col  = lane & 15;          // s within strip / MFMA col
    const int quad = lane >> 4;
    // staging roles
    const int mc   = lane >> 2;          // m-chunk 0..15 (8 m-rows each)
    const int sq   = lane & 3;           // s-quad 0..3
    unsigned short* X = &Xs[w][0];

    const int wgid = blockIdx.x * 8 + w;

    // per-lane LN params (c = 16*mt + 4*quad + rr) -- hoisted, loop-invariant
    f4 b4[8], g4[8], e4[8];
    #pragma unroll
    for (int mt = 0; mt < 8; ++mt) {
        b4[mt] = *(const f4*)(bp  + 16 * mt + 4 * quad);
        g4[mt] = *(const f4*)(gp  + 16 * mt + 4 * quad);
        e4[mt] = *(const f4*)(bep + 16 * mt + 4 * quad);
    }

    // ---- prologue: load first strip
    f4 r[8];
    int sid = wgid;
    if (sid < NSTRIP) {
        const int g  = sid / SPG;
        const int s0 = (sid - g * SPG) * 16;
        int sb = s0 + 4 * sq; if (sb > SEQ - 4) sb = SEQ - 4;
        const float* xp = x + (size_t)g * (C * SEQ) + (size_t)(mc * 8) * SEQ + sb;
        #pragma unroll
        for (int rr = 0; rr < 8; ++rr) r[rr] = *(const f4*)(xp + (size_t)rr * SEQ);
    }

    #pragma unroll 1
    for (; sid < NSTRIP; sid += NWAVE) {
        const int g  = sid / SPG;
        const int s0 = (sid - g * SPG) * 16;
        float* og = out + (size_t)g * (C * SEQ);

        // ---- consume prefetch: 8x4 in-register transpose -> bf16, private LDS
        #pragma unroll
        for (int j = 0; j < 4; ++j) {
            const int sl = 4 * sq + j;
            uint4 pk;
            pk.x = cvt2(r[0][j], r[1][j]);
            pk.y = cvt2(r[2][j], r[3][j]);
            pk.z = cvt2(r[4][j], r[5][j]);
            pk.w = cvt2(r[6][j], r[7][j]);
            *(uint4*)&X[sl * C + swz(sl, mc) * 8] = pk;
        }

        // ---- issue NEXT strip's loads now, BEFORE this strip's stores, so the
        // next load-wait is vmcnt(32) and stores stay in flight. r[] was already
        // consumed above; all hazards are wave-local (compiler-tracked).
        {
            int nsid = sid + NWAVE; if (nsid >= NSTRIP) nsid = sid;  // harmless dup
            const int ng  = nsid / SPG;
            const int ns0 = (nsid - ng * SPG) * 16;
            int sb = ns0 + 4 * sq; if (sb > SEQ - 4) sb = SEQ - 4;
            const float* xp = x + (size_t)ng * (C * SEQ) + (size_t)(mc * 8) * SEQ + sb;
            #pragma unroll
            for (int rr = 0; rr < 8; ++rr) r[rr] = *(const f4*)(xp + (size_t)rr * SEQ);
        }

        // ---- MFMA: D = W x X^T, col(lane&15)=s, row(4*quad+rr)=c
        f4 acc[8];
        #pragma unroll
        for (int mt = 0; mt < 8; ++mt) acc[mt] = (f4){0.f, 0.f, 0.f, 0.f};

        #pragma unroll 1
        for (int kc = 0; kc < 4; ++kc) {
            short8 xb = *(const short8*)&X[col * C + swz(col, 4 * kc + quad) * 8];
            short8 a[8];
            #pragma unroll
            for (int mt = 0; mt < 8; ++mt) {
                const int row = 16 * mt + col;
                a[mt] = *(const short8*)&Wl[row * C + swz(row, 4 * kc + quad) * 8];
            }
            #pragma unroll
            for (int mt = 0; mt < 8; ++mt)
                acc[mt] = __builtin_amdgcn_mfma_f32_16x16x32_bf16(a[mt], xb, acc[mt], 0, 0, 0);
        }

        // ---- bias + in-wave per-s LayerNorm (c spans quads + regs)
        #pragma unroll
        for (int mt = 0; mt < 8; ++mt)
            #pragma unroll
            for (int rr = 0; rr < 4; ++rr) acc[mt][rr] += b4[mt][rr];

        float s = 0.f, q = 0.f;
        #pragma unroll
        for (int mt = 0; mt < 8; ++mt)
            #pragma unroll
            for (int rr = 0; rr < 4; ++rr) {
                float y = acc[mt][rr];
                s += y; q += y * y;
            }
        s += __shfl_xor(s, 16); q += __shfl_xor(q, 16);
        s += __shfl_xor(s, 32); q += __shfl_xor(q, 32);
        const float mean = s * (1.0f / C);
        const float var  = q * (1.0f / C) - mean * mean;
        const float rstd = rsqrtf(var + 1e-5f);

        // ---- scale/shift + store: 16 lanes x 4B contiguous = full 64B sector
        const int sg = s0 + col;
        if (sg < SEQ) {
            #pragma unroll
            for (int mt = 0; mt < 8; ++mt) {
                #pragma unroll
                for (int rr = 0; rr < 4; ++rr) {
                    const int c = 16 * mt + 4 * quad + rr;
                    og[(size_t)c * SEQ + sg] =
                        (acc[mt][rr] - mean) * rstd * g4[mt][rr] + e4[mt][rr];
                }
            }
        }
    }
}

extern "C" void kernel_launch(void* const* d_in, const int* in_sizes, int n_in,
                              void* d_out, int out_size, void* d_ws, size_t ws_size,
                              hipStream_t stream) {
    // inputs: x, Wq, bq, gq, betaq, Wk, bk, gk, betak, Wp, bp, gp, betap
    const float* x   = (const float*)d_in[0];
    const float* Wp  = (const float*)d_in[9];
    const float* bp  = (const float*)d_in[10];
    const float* gp  = (const float*)d_in[11];
    const float* bep = (const float*)d_in[12];
    float* out = (float*)d_out;
    unsigned short* wbf = (unsigned short*)d_ws;   // 32 KB bf16 weights (swizzled)

    hipLaunchKernelGGL(cvt_wp, dim3(64), dim3(256), 0, stream, Wp, wbf);

    hipLaunchKernelGGL(gemm_ln_mfma, dim3(512), dim3(512), 0, stream,
                       x, wbf, bp, gp, bep, out);
}

// Round 6
// 459.727 us; speedup vs baseline: 1.0194x; 1.0194x over previous
//
#include <hip/hip_runtime.h>

// channel_attention reduces to: out[g,c,s] = LN_c( sum_m Wp[c][m]*x[g][m][s] + bp ) * gp + betap
// (softmax row-sums==1 make q/k/atten dead). g in [0,128); per group GEMM 128x3000x128 + LN.
//
// V7 = V6's autonomous-wave pipeline (proved 3.5 TB/s controller rate; no barriers
// in steady state) FIXED for line granularity (V6 inflated FETCH 2.04x / WRITE 1.66x
// with 64-B per-row wave footprints):
//  - strip = 32 s: every wave load/store touches 128 B contiguous per row.
//  - group-clustered schedule: 16 waves on the SAME XCD work adjacent strips of the
//    same group concurrently -> straddled/partial lines (12000-B out rows are only
//    32-B aligned) are completed by a neighbor while still L2-resident.
//  - next-strip loads issued before the store phase: their vmcnt wait retires only
//    the oldest (load) entries; stores stay in flight.

#define C    128
#define SEQ  3000
#define NG   128
#define ST   32                          // strip width in s
#define SPG  ((SEQ + ST - 1) / ST)       // 94 strips per group (last is 24 wide)
#define WPG  16                          // concurrent waves per group
#define GPX  16                          // groups per XCD

typedef float f4 __attribute__((ext_vector_type(4)));
typedef short short8 __attribute__((ext_vector_type(8)));

__device__ __forceinline__ unsigned short f2bf(float f) {
    union { float f; unsigned u; } v; v.f = f;
    unsigned r = v.u + 0x7fffu + ((v.u >> 16) & 1u);   // RNE
    return (unsigned short)(r >> 16);
}

// packed f32x2 -> bf16x2, RNE
__device__ __forceinline__ unsigned cvt2(float lo, float hi) {
    unsigned r;
    asm("v_cvt_pk_bf16_f32 %0, %1, %2" : "=v"(r) : "v"(lo), "v"(hi));
    return r;
}

// 16B-chunk XOR swizzle (V1-proven <=2-way for both the transpose-write and the
// fragment-read patterns; rows 16..31 are the rows 0..15 pattern XOR 4 -> same spread).
__device__ __forceinline__ int swz(int row, int chunk) {
    return chunk ^ ((row ^ (row >> 2)) & 15);
}

// W in bf16 with the LDS swizzle pre-applied (GEMM W-stage = pure linear copy).
__global__ void cvt_wp(const float* __restrict__ Wp, unsigned short* __restrict__ out) {
    int i = blockIdx.x * 256 + threadIdx.x;
    if (i >= C * C) return;
    int c = i >> 7, r = i & 127, ch = r >> 3, j = r & 7;
    out[c * C + swz(c, ch) * 8 + j] = f2bf(Wp[i]);
}

__global__ __launch_bounds__(256, 2) void gemm_ln_mfma(
    const float* __restrict__ x,             // [NG][C][SEQ] fp32
    const unsigned short* __restrict__ wbf,  // [C][C] bf16, swizzled chunks
    const float* __restrict__ bp,
    const float* __restrict__ gp,
    const float* __restrict__ bep,
    float* __restrict__ out)                 // [NG][C][SEQ] fp32
{
    __shared__ __align__(16) unsigned short Wl[C * C];      // 32 KB shared W
    __shared__ __align__(16) unsigned short Xs[4][ST * C];  // 4 x 8 KB wave-private

    const int t = threadIdx.x;

    // ---- stage W once (linear copy), single barrier of the whole kernel
    {
        const uint4* wsrc = (const uint4*)wbf;
        uint4* wdst = (uint4*)Wl;
        #pragma unroll
        for (int i = 0; i < 8; ++i) wdst[t + 256 * i] = wsrc[t + 256 * i];
    }
    __syncthreads();

    const int w    = t >> 6;
    const int lane = t & 63;
    // compute roles
    const int col  = lane & 15;
    const int quad = lane >> 4;
    // staging roles: 8 s-quads x 8 m-chunks; one batch = 64 m-rows x 32 s,
    // 128 B contiguous per m-row.
    const int sq   = lane & 7;
    const int mc   = lane >> 3;
    unsigned short* X = &Xs[w][0];

    // ---- group-clustered schedule: block b -> XCD b&7 (perf heuristic only);
    // 16 groups per XCD; 16 same-XCD waves per group on adjacent strips.
    const int b     = blockIdx.x;
    const int xcd   = b & 7;
    const int wx    = (b >> 3) * 4 + w;          // 0..255 within XCD
    const int g     = xcd * GPX + (wx >> 4);     // group
    const int gwave = wx & 15;                   // position among the 16 group waves
    const float* xg = x   + (size_t)g * (C * SEQ);
    float*       og = out + (size_t)g * (C * SEQ);

    // ---- prologue: load first strip, both 64-row batches (16 f4 in flight)
    f4 r0[8], r1[8];
    int sid = gwave;
    {
        int sb = sid * ST + 4 * sq;              // <= 2976+28 < SEQ-3, no clamp needed
        const float* p0 = xg + (size_t)(mc * 8) * SEQ + sb;
        const float* p1 = p0 + (size_t)64 * SEQ;
        #pragma unroll
        for (int rr = 0; rr < 8; ++rr) r0[rr] = *(const f4*)(p0 + (size_t)rr * SEQ);
        #pragma unroll
        for (int rr = 0; rr < 8; ++rr) r1[rr] = *(const f4*)(p1 + (size_t)rr * SEQ);
    }

    #pragma unroll 1
    for (; sid < SPG; sid += WPG) {
        const int s0 = sid * ST;

        // ---- consume prefetch: transpose+cvt both batches into private LDS.
        // pk[j] = 8 consecutive bf16 m-values at local s = 4*sq+j, chunk mc (+8 for bat1).
        #pragma unroll
        for (int j = 0; j < 4; ++j) {
            const int sl = 4 * sq + j;
            uint4 pk;
            pk.x = cvt2(r0[0][j], r0[1][j]);
            pk.y = cvt2(r0[2][j], r0[3][j]);
            pk.z = cvt2(r0[4][j], r0[5][j]);
            pk.w = cvt2(r0[6][j], r0[7][j]);
            *(uint4*)&X[sl * C + swz(sl, mc) * 8] = pk;
        }
        #pragma unroll
        for (int j = 0; j < 4; ++j) {
            const int sl = 4 * sq + j;
            uint4 pk;
            pk.x = cvt2(r1[0][j], r1[1][j]);
            pk.y = cvt2(r1[2][j], r1[3][j]);
            pk.z = cvt2(r1[4][j], r1[5][j]);
            pk.w = cvt2(r1[6][j], r1[7][j]);
            *(uint4*)&X[sl * C + swz(sl, 8 + mc) * 8] = pk;
        }

        // ---- issue NEXT strip's 16 loads now (before MFMA + stores): their wait
        // next iteration retires only these oldest vmem entries.
        {
            int nsid = sid + WPG; if (nsid >= SPG) nsid = sid;   // harmless dup
            int sb = nsid * ST + 4 * sq;
            if (sb > SEQ - 4) sb = SEQ - 4;                      // tail strip clamp
            const float* p0 = xg + (size_t)(mc * 8) * SEQ + sb;
            const float* p1 = p0 + (size_t)64 * SEQ;
            #pragma unroll
            for (int rr = 0; rr < 8; ++rr) r0[rr] = *(const f4*)(p0 + (size_t)rr * SEQ);
            #pragma unroll
            for (int rr = 0; rr < 8; ++rr) r1[rr] = *(const f4*)(p1 + (size_t)rr * SEQ);
        }

        // ---- MFMA: D = W x X^T. col(lane&15)=s, row(4*quad+rr)=c. acc[nt][mt],
        // nt = s half (16 each), mt = c tile.
        f4 acc[2][8];
        #pragma unroll
        for (int nt = 0; nt < 2; ++nt)
            #pragma unroll
            for (int mt = 0; mt < 8; ++mt) acc[nt][mt] = (f4){0.f, 0.f, 0.f, 0.f};

        #pragma unroll 1
        for (int kc = 0; kc < 4; ++kc) {
            short8 xb[2];
            #pragma unroll
            for (int nt = 0; nt < 2; ++nt) {
                const int row = nt * 16 + col;
                xb[nt] = *(const short8*)&X[row * C + swz(row, 4 * kc + quad) * 8];
            }
            short8 a[8];
            #pragma unroll
            for (int mt = 0; mt < 8; ++mt) {
                const int row = 16 * mt + col;
                a[mt] = *(const short8*)&Wl[row * C + swz(row, 4 * kc + quad) * 8];
            }
            #pragma unroll
            for (int nt = 0; nt < 2; ++nt)
                #pragma unroll
                for (int mt = 0; mt < 8; ++mt)
                    acc[nt][mt] = __builtin_amdgcn_mfma_f32_16x16x32_bf16(
                        a[mt], xb[nt], acc[nt][mt], 0, 0, 0);
        }

        // ---- bias + per-s LayerNorm (c spans regs (mt,rr) and quads; shfl 16/32
        // reduces across quads at fixed col -> per-column independent)
        #pragma unroll
        for (int mt = 0; mt < 8; ++mt) {
            const f4 b4 = *(const f4*)(bp + 16 * mt + 4 * quad);
            #pragma unroll
            for (int nt = 0; nt < 2; ++nt)
                #pragma unroll
                for (int rr = 0; rr < 4; ++rr) acc[nt][mt][rr] += b4[rr];
        }

        float mean[2], rstd[2];
        #pragma unroll
        for (int nt = 0; nt < 2; ++nt) {
            float s = 0.f, q = 0.f;
            #pragma unroll
            for (int mt = 0; mt < 8; ++mt)
                #pragma unroll
                for (int rr = 0; rr < 4; ++rr) {
                    float y = acc[nt][mt][rr];
                    s += y; q += y * y;
                }
            s += __shfl_xor(s, 16); q += __shfl_xor(q, 16);
            s += __shfl_xor(s, 32); q += __shfl_xor(q, 32);
            float m = s * (1.0f / C);
            float v = q * (1.0f / C) - m * m;
            mean[nt] = m;
            rstd[nt] = rsqrtf(v + 1e-5f);
        }

        // ---- scale/shift + store: per c-row the two 64-B halves (nt=0/1) issue
        // back-to-back -> combine to 128 B in L2.
        #pragma unroll
        for (int mt = 0; mt < 8; ++mt) {
            const f4 g4 = *(const f4*)(gp  + 16 * mt + 4 * quad);
            const f4 e4 = *(const f4*)(bep + 16 * mt + 4 * quad);
            #pragma unroll
            for (int nt = 0; nt < 2; ++nt) {
                const int sg = s0 + nt * 16 + col;
                if (sg < SEQ) {
                    #pragma unroll
                    for (int rr = 0; rr < 4; ++rr) {
                        const int c = 16 * mt + 4 * quad + rr;
                        og[(size_t)c * SEQ + sg] =
                            (acc[nt][mt][rr] - mean[nt]) * rstd[nt] * g4[rr] + e4[rr];
                    }
                }
            }
        }
    }
}

extern "C" void kernel_launch(void* const* d_in, const int* in_sizes, int n_in,
                              void* d_out, int out_size, void* d_ws, size_t ws_size,
                              hipStream_t stream) {
    // inputs: x, Wq, bq, gq, betaq, Wk, bk, gk, betak, Wp, bp, gp, betap
    const float* x   = (const float*)d_in[0];
    const float* Wp  = (const float*)d_in[9];
    const float* bp  = (const float*)d_in[10];
    const float* gp  = (const float*)d_in[11];
    const float* bep = (const float*)d_in[12];
    float* out = (float*)d_out;
    unsigned short* wbf = (unsigned short*)d_ws;   // 32 KB bf16 weights (swizzled)

    hipLaunchKernelGGL(cvt_wp, dim3(64), dim3(256), 0, stream, Wp, wbf);

    hipLaunchKernelGGL(gemm_ln_mfma, dim3(512), dim3(256), 0, stream,
                       x, wbf, bp, gp, bep, out);
}

// Round 7
// 446.340 us; speedup vs baseline: 1.0500x; 1.0300x over previous
//
#include <hip/hip_runtime.h>

// channel_attention reduces to: out[g,c,s] = LN_c( sum_m Wp[c][m]*x[g][m][s] + bp ) * gp + betap
// (softmax row-sums==1 make q/k/atten dead). g in [0,128); per group GEMM 128x3000x128 + LN.
//
// V8 = V4 (best: 124us, exact FETCH 115 / WRITE 194 MB) with Wl removed from LDS.
// Evidence V2-V7: (a) V4's patterns are the only ones with exact traffic --
// 512-B/row load footprint, scalar s-in-lane stores (4x64B full sectors/instr);
// (b) autonomous small strips hit 3.5 TB/s controller rate but inflate traffic
// 1.6-2x (12000-B rows are only 32-B aligned -> line straddle); (c) V2 proved
// W-fragment reads from global are harmless on fetch (L1/L2-resident 32 KB).
// So: halve LDS (drop Wl) -> 4 independent naturally-staggered blocks/CU,
// 32 waves/CU (was 2 blocks/16 waves). Single-variable change vs V4.

#define C    128
#define SEQ  3000
#define NG   128
#define NT   128                       // columns per block
#define NBLK ((SEQ + NT - 1) / NT)     // 24

typedef float f4 __attribute__((ext_vector_type(4)));
typedef short short8 __attribute__((ext_vector_type(8)));

__device__ __forceinline__ unsigned short f2bf(float f) {
    union { float f; unsigned u; } v; v.f = f;
    unsigned r = v.u + 0x7fffu + ((v.u >> 16) & 1u);   // RNE
    return (unsigned short)(r >> 16);
}

// packed f32x2 -> bf16x2, RNE
__device__ __forceinline__ unsigned cvt2(float lo, float hi) {
    unsigned r;
    asm("v_cvt_pk_bf16_f32 %0, %1, %2" : "=v"(r) : "v"(lo), "v"(hi));
    return r;
}

// 16B-chunk XOR swizzle for the X tile: injective over 16 consecutive rows (frag
// reads) and over the transpose-write lane pattern, both <=2-way (V1-proven).
__device__ __forceinline__ int swz(int row, int chunk) {
    return chunk ^ ((row ^ (row >> 2)) & 15);
}

// W in bf16, LINEAR [c][m] layout (fragments read straight from global in the GEMM).
__global__ void cvt_wp(const float* __restrict__ Wp, unsigned short* __restrict__ out) {
    int i = blockIdx.x * 256 + threadIdx.x;
    if (i < C * C) out[i] = f2bf(Wp[i]);
}

__global__ __launch_bounds__(512, 4) void gemm_ln_mfma(
    const float* __restrict__ x,             // [NG][C][SEQ] fp32
    const unsigned short* __restrict__ wbf,  // [C][C] bf16 linear
    const float* __restrict__ bp,
    const float* __restrict__ gp,
    const float* __restrict__ bep,
    float* __restrict__ out)                 // [NG][C][SEQ] fp32
{
    __shared__ __align__(16) unsigned short Xl[NT * C];  // 32 KB, [s][m] swizzled

    const int g  = blockIdx.y;
    const int s0 = blockIdx.x * NT;
    const float* xg = x + (size_t)g * (C * SEQ);
    float* og = out + (size_t)g * (C * SEQ);
    const int t = threadIdx.x;

    // ---- stage X transposed: thread owns (m-chunk, s-quad); 8x4 in-register
    // transpose; 8 f4 loads (512 B contiguous per row across lanes), 4 x 16B LDS writes.
    {
        const int sq  = t & 31;              // s-quad 0..31 (consecutive lanes -> coalesced)
        const int mc  = t >> 5;              // m-chunk 0..15
        const int s_loc  = 4 * sq;
        const int s_glob = s0 + s_loc;
        const bool valid = (s_glob + 3) < SEQ;   // SEQ%4==0 -> quad all-or-nothing
        f4 r[8];
        const float* xp = xg + (size_t)(mc * 8) * SEQ + s_glob;
        #pragma unroll
        for (int rr = 0; rr < 8; ++rr) {
            if (valid) r[rr] = *(const f4*)(xp + (size_t)rr * SEQ);
            else       r[rr] = (f4){0.f, 0.f, 0.f, 0.f};
        }
        #pragma unroll
        for (int j = 0; j < 4; ++j) {
            const int sl = s_loc + j;
            uint4 pk;
            pk.x = cvt2(r[0][j], r[1][j]);
            pk.y = cvt2(r[2][j], r[3][j]);
            pk.z = cvt2(r[4][j], r[5][j]);
            pk.w = cvt2(r[6][j], r[7][j]);
            *(uint4*)&Xl[sl * C + swz(sl, mc) * 8] = pk;
        }
    }
    __syncthreads();

    // ---- MFMA: 8 waves, wave owns 16-s strip x all 128 channels (LN in-wave).
    // D = W x X^T: col(lane&15) = s, row(4*quad+rr) = c. A-frag (W) straight from
    // global: W[c=16mt+col][m = 32kc + 8quad + 0..7] -- L1/L2-resident 32 KB.
    const int w    = t >> 6;
    const int lane = t & 63;
    const int col  = lane & 15;
    const int quad = lane >> 4;

    f4 acc[8];   // [mt = c-tile]
    #pragma unroll
    for (int mt = 0; mt < 8; ++mt) acc[mt] = (f4){0.f, 0.f, 0.f, 0.f};

    const unsigned short* wl = wbf + col * C + quad * 8;
    const int srow = 16 * w + col;

    #pragma unroll 1
    for (int kc = 0; kc < 4; ++kc) {
        short8 xb = *(const short8*)&Xl[srow * C + swz(srow, 4 * kc + quad) * 8];
        short8 a[8];
        #pragma unroll
        for (int mt = 0; mt < 8; ++mt)
            a[mt] = *(const short8*)(wl + mt * 16 * C + kc * 32);
        #pragma unroll
        for (int mt = 0; mt < 8; ++mt)
            acc[mt] = __builtin_amdgcn_mfma_f32_16x16x32_bf16(a[mt], xb, acc[mt], 0, 0, 0);
    }

    // ---- bias + in-wave per-s LayerNorm (c spans quads + regs; reduce over
    // quads at fixed col via shfl 16/32)
    #pragma unroll
    for (int mt = 0; mt < 8; ++mt) {
        const f4 b4 = *(const f4*)(bp + 16 * mt + 4 * quad);
        #pragma unroll
        for (int rr = 0; rr < 4; ++rr) acc[mt][rr] += b4[rr];
    }

    float s = 0.f, q = 0.f;
    #pragma unroll
    for (int mt = 0; mt < 8; ++mt)
        #pragma unroll
        for (int rr = 0; rr < 4; ++rr) {
            float y = acc[mt][rr];
            s += y; q += y * y;
        }
    s += __shfl_xor(s, 16); q += __shfl_xor(q, 16);
    s += __shfl_xor(s, 32); q += __shfl_xor(q, 32);
    const float mean = s * (1.0f / C);
    const float var  = q * (1.0f / C) - mean * mean;
    const float rstd = rsqrtf(var + 1e-5f);

    // ---- scale/shift + store: 16 lanes x 4B contiguous = full 64B sector/instr
    const int sg = s0 + srow;
    if (sg < SEQ) {
        #pragma unroll
        for (int mt = 0; mt < 8; ++mt) {
            const f4 g4 = *(const f4*)(gp  + 16 * mt + 4 * quad);
            const f4 e4 = *(const f4*)(bep + 16 * mt + 4 * quad);
            #pragma unroll
            for (int rr = 0; rr < 4; ++rr) {
                const int c = 16 * mt + 4 * quad + rr;
                og[(size_t)c * SEQ + sg] =
                    (acc[mt][rr] - mean) * rstd * g4[rr] + e4[rr];
            }
        }
    }
}

extern "C" void kernel_launch(void* const* d_in, const int* in_sizes, int n_in,
                              void* d_out, int out_size, void* d_ws, size_t ws_size,
                              hipStream_t stream) {
    // inputs: x, Wq, bq, gq, betaq, Wk, bk, gk, betak, Wp, bp, gp, betap
    const float* x   = (const float*)d_in[0];
    const float* Wp  = (const float*)d_in[9];
    const float* bp  = (const float*)d_in[10];
    const float* gp  = (const float*)d_in[11];
    const float* bep = (const float*)d_in[12];
    float* out = (float*)d_out;
    unsigned short* wbf = (unsigned short*)d_ws;   // 32 KB bf16 weights (linear)

    hipLaunchKernelGGL(cvt_wp, dim3(64), dim3(256), 0, stream, Wp, wbf);

    dim3 grid(NBLK, NG);
    hipLaunchKernelGGL(gemm_ln_mfma, grid, dim3(512), 0, stream,
                       x, wbf, bp, gp, bep, out);
}